// Round 1
// baseline (660.608 us; speedup 1.0000x reference)
//
#include <hip/hip_runtime.h>
#include <hip/hip_bf16.h>

#define N_NODES 50000
#define E_BASE  800000
#define E_TOT   850000   // + self loops
#define IN_DIM  58
#define HID     100

// ---------------------------------------------------------------- lin1 + relu
__global__ __launch_bounds__(256) void lin1_kernel(
    const float* __restrict__ x, const float* __restrict__ w,
    const float* __restrict__ b, float* __restrict__ h) {
  __shared__ float wl[IN_DIM * HID];  // [k][j] layout: consecutive j => consecutive banks
  __shared__ float bl[HID];
  int tid = threadIdx.x;
  for (int i = tid; i < IN_DIM * HID; i += 256) {
    int j = i / IN_DIM, k = i - j * IN_DIM;   // w row-major [j][k]
    wl[k * HID + j] = w[i];
  }
  if (tid < HID) bl[tid] = b[tid];
  __syncthreads();
  int idx = blockIdx.x * 256 + tid;
  if (idx >= N_NODES * HID) return;
  int n = idx / HID, j = idx - n * HID;
  const float* xr = x + n * IN_DIM;
  float acc = bl[j];
#pragma unroll
  for (int k = 0; k < IN_DIM; ++k) acc = fmaf(xr[k], wl[k * HID + j], acc);
  h[idx] = fmaxf(acc, 0.f);
}

// ------------------------------------------------------- per-row inverse norm
__global__ __launch_bounds__(256) void invnorm_kernel(
    const float* __restrict__ h, float* __restrict__ invn, int n) {
  int wid = (blockIdx.x * blockDim.x + threadIdx.x) >> 6;
  int lane = threadIdx.x & 63;
  if (wid >= n) return;
  const float* hr = h + wid * HID;
  float s = 0.f;
  if (lane < HID) { float v = hr[lane]; s = v * v; }
  if (lane + 64 < HID) { float v = hr[lane + 64]; s = fmaf(v, v, s); }
#pragma unroll
  for (int off = 32; off; off >>= 1) s += __shfl_xor(s, off);
  if (lane == 0) invn[wid] = 1.f / fmaxf(sqrtf(s), 1e-12f);
}

// --------------------------------------------------------- in-degree histogram
__global__ __launch_bounds__(256) void hist_kernel(
    const int* __restrict__ ei, int* __restrict__ deg) {
  int e = blockIdx.x * blockDim.x + threadIdx.x;
  if (e >= E_TOT) return;
  int dst = (e < E_BASE) ? ei[E_BASE + e] : (e - E_BASE);
  atomicAdd(&deg[dst], 1);
}

// -------------------------------------------- single-block exclusive prefix sum
__global__ __launch_bounds__(1024) void scan_kernel(
    const int* __restrict__ deg, int* __restrict__ rowstart, int n) {
  __shared__ int part[1024];
  int tid = threadIdx.x;
  const int per = (n + 1023) >> 10;
  int base = tid * per;
  int s = 0;
  for (int i = 0; i < per; ++i) {
    int idx = base + i;
    if (idx < n) s += deg[idx];
  }
  part[tid] = s;
  __syncthreads();
  for (int off = 1; off < 1024; off <<= 1) {
    int v = (tid >= off) ? part[tid - off] : 0;
    __syncthreads();
    part[tid] += v;
    __syncthreads();
  }
  int run = (tid == 0) ? 0 : part[tid - 1];
  for (int i = 0; i < per; ++i) {
    int idx = base + i;
    if (idx < n) { rowstart[idx] = run; run += deg[idx]; }
  }
  if (tid == 1023) rowstart[n] = part[1023];
}

// --------------------------------------------------- scatter edges into CSR
__global__ __launch_bounds__(256) void scatter_kernel(
    const int* __restrict__ ei, int* __restrict__ cur,
    int* __restrict__ src_csr, int* __restrict__ dst_csr) {
  int e = blockIdx.x * blockDim.x + threadIdx.x;
  if (e >= E_TOT) return;
  int src, dst;
  if (e < E_BASE) { src = ei[e]; dst = ei[E_BASE + e]; }
  else            { src = dst = e - E_BASE; }
  int p = atomicAdd(&cur[dst], 1);
  src_csr[p] = src;
  dst_csr[p] = dst;
}

// ------------------------------------- per-edge attention logit (16 lanes/edge)
__global__ __launch_bounds__(256) void alpha_kernel(
    const float* __restrict__ h, const float* __restrict__ invn,
    const int* __restrict__ src_csr, const int* __restrict__ dst_csr,
    float* __restrict__ alpha, const float* __restrict__ beta_ptr) {
  int g = (blockIdx.x * 256 + threadIdx.x) >> 4;
  int l = threadIdx.x & 15;
  if (g >= E_TOT) return;
  int s = src_csr[g], d = dst_csr[g];
  const float* hs = h + s * HID;
  const float* hd = h + d * HID;
  float acc = 0.f;
  for (int k = l; k < HID; k += 16) acc = fmaf(hs[k], hd[k], acc);
#pragma unroll
  for (int off = 8; off; off >>= 1) acc += __shfl_xor(acc, off);
  if (l == 0) {
    float beta = beta_ptr ? beta_ptr[0] : 1.0f;
    alpha[g] = beta * acc * invn[s] * invn[d];
  }
}

// ---------------- per-node softmax (max/sum) + weighted aggregation, CSR order
__global__ __launch_bounds__(128) void agg_kernel(
    const float* __restrict__ h, const float* __restrict__ alpha,
    const int* __restrict__ src_csr, const int* __restrict__ rowstart,
    float* __restrict__ out) {
  int node = blockIdx.x;
  int start = rowstart[node];
  int end = rowstart[node + 1];
  int tid = threadIdx.x;
  __shared__ float redm[2], reds[2];
  __shared__ float wl[128];
  __shared__ int sl[128];
  // segment max
  float m = -1e30f;
  for (int p = start + tid; p < end; p += 128) m = fmaxf(m, alpha[p]);
#pragma unroll
  for (int off = 32; off; off >>= 1) m = fmaxf(m, __shfl_xor(m, off));
  if ((tid & 63) == 0) redm[tid >> 6] = m;
  __syncthreads();
  m = fmaxf(redm[0], redm[1]);
  // segment sum of exp
  float s = 0.f;
  for (int p = start + tid; p < end; p += 128) s += __expf(alpha[p] - m);
#pragma unroll
  for (int off = 32; off; off >>= 1) s += __shfl_xor(s, off);
  if ((tid & 63) == 0) reds[tid >> 6] = s;
  __syncthreads();
  float invden = 1.f / (reds[0] + reds[1] + 1e-16f);
  // weighted aggregation, chunks of 128 edges staged in LDS
  float acc = 0.f;
  for (int cs = start; cs < end; cs += 128) {
    int cn = min(128, end - cs);
    __syncthreads();
    if (tid < cn) {
      wl[tid] = __expf(alpha[cs + tid] - m) * invden;
      sl[tid] = src_csr[cs + tid];
    }
    __syncthreads();
    if (tid < HID) {
      for (int i = 0; i < cn; ++i) acc += wl[i] * h[sl[i] * HID + tid];
    }
  }
  if (tid < HID) out[node * HID + tid] = acc;
}

// ------------------------------------------------------------------ final lin2
__global__ __launch_bounds__(256) void lin2_kernel(
    const float* __restrict__ h, const float* __restrict__ w2,
    const float* __restrict__ b2, float* __restrict__ out, int n) {
  int wid = (blockIdx.x * blockDim.x + threadIdx.x) >> 6;
  int lane = threadIdx.x & 63;
  if (wid >= n) return;
  const float* hr = h + wid * HID;
  float s = 0.f;
  if (lane < HID) s = hr[lane] * w2[lane];
  if (lane + 64 < HID) s = fmaf(hr[lane + 64], w2[lane + 64], s);
#pragma unroll
  for (int off = 32; off; off >>= 1) s += __shfl_xor(s, off);
  if (lane == 0) out[wid] = s + b2[0];
}

extern "C" void kernel_launch(void* const* d_in, const int* in_sizes, int n_in,
                              void* d_out, int out_size, void* d_ws, size_t ws_size,
                              hipStream_t stream) {
  const float* x      = (const float*)d_in[0];
  const int*   ei     = (const int*)d_in[1];     // [2][E_BASE], int32 (x64 off)
  const float* lin1_w = (const float*)d_in[2];
  const float* lin1_b = (const float*)d_in[3];
  const float* beta2  = (const float*)d_in[4];
  const float* lin2_w = (const float*)d_in[5];
  const float* lin2_b = (const float*)d_in[6];
  float* out = (float*)d_out;

  // workspace layout (all 4B elems)
  float* ws = (float*)d_ws;
  size_t off = 0;
  float* h1    = ws + off; off += (size_t)N_NODES * HID;   // 5,000,000
  float* h2    = ws + off; off += (size_t)N_NODES * HID;   // 5,000,000
  float* invn  = ws + off; off += N_NODES;
  float* alpha = ws + off; off += E_TOT;
  int* iws      = (int*)(ws + off);
  int* deg      = iws;                 // N
  int* rowstart = deg + N_NODES;       // N+1
  int* cur      = rowstart + N_NODES + 1;  // N
  int* src_csr  = cur + N_NODES;       // E_TOT
  int* dst_csr  = src_csr + E_TOT;     // E_TOT

  // ---- lin1 + relu
  lin1_kernel<<<(N_NODES * HID + 255) / 256, 256, 0, stream>>>(x, lin1_w, lin1_b, h1);

  // ---- build CSR by dst (reused by both props)
  hipMemsetAsync(deg, 0, N_NODES * sizeof(int), stream);
  hist_kernel<<<(E_TOT + 255) / 256, 256, 0, stream>>>(ei, deg);
  scan_kernel<<<1, 1024, 0, stream>>>(deg, rowstart, N_NODES);
  hipMemcpyAsync(cur, rowstart, N_NODES * sizeof(int), hipMemcpyDeviceToDevice, stream);
  scatter_kernel<<<(E_TOT + 255) / 256, 256, 0, stream>>>(ei, cur, src_csr, dst_csr);

  // ---- prop 1 (beta = 1.0)
  invnorm_kernel<<<(N_NODES + 3) / 4, 256, 0, stream>>>(h1, invn, N_NODES);
  alpha_kernel<<<(E_TOT + 15) / 16, 256, 0, stream>>>(h1, invn, src_csr, dst_csr, alpha, nullptr);
  agg_kernel<<<N_NODES, 128, 0, stream>>>(h1, alpha, src_csr, rowstart, h2);

  // ---- prop 2 (beta = beta2[0])
  invnorm_kernel<<<(N_NODES + 3) / 4, 256, 0, stream>>>(h2, invn, N_NODES);
  alpha_kernel<<<(E_TOT + 15) / 16, 256, 0, stream>>>(h2, invn, src_csr, dst_csr, alpha, beta2);
  agg_kernel<<<N_NODES, 128, 0, stream>>>(h2, alpha, src_csr, rowstart, h1 /* reuse as h3 */);

  // ---- lin2
  lin2_kernel<<<(N_NODES + 3) / 4, 256, 0, stream>>>(h1, lin2_w, lin2_b, out, N_NODES);
}

// Round 2
// 641.879 us; speedup vs baseline: 1.0292x; 1.0292x over previous
//
#include <hip/hip_runtime.h>
#include <hip/hip_bf16.h>

#define N_NODES 50000
#define E_BASE  800000
#define E_TOT   850000   // + self loops
#define IN_DIM  58
#define HID     100
#define SCAN_BLOCKS ((N_NODES + 255) / 256)   // 196

// ---------------------------------------------------------------- lin1 + relu
__global__ __launch_bounds__(256) void lin1_kernel(
    const float* __restrict__ x, const float* __restrict__ w,
    const float* __restrict__ b, float* __restrict__ h) {
  __shared__ float wl[IN_DIM * HID];  // [k][j] layout
  __shared__ float bl[HID];
  int tid = threadIdx.x;
  for (int i = tid; i < IN_DIM * HID; i += 256) {
    int j = i / IN_DIM, k = i - j * IN_DIM;   // w row-major [j][k]
    wl[k * HID + j] = w[i];
  }
  if (tid < HID) bl[tid] = b[tid];
  __syncthreads();
  int idx = blockIdx.x * 256 + tid;
  if (idx >= N_NODES * HID) return;
  int n = idx / HID, j = idx - n * HID;
  const float* xr = x + n * IN_DIM;
  float acc = bl[j];
#pragma unroll
  for (int k = 0; k < IN_DIM; ++k) acc = fmaf(xr[k], wl[k * HID + j], acc);
  h[idx] = fmaxf(acc, 0.f);
}

// ------------------------------------------------------- per-row inverse norm
__global__ __launch_bounds__(256) void invnorm_kernel(
    const float* __restrict__ h, float* __restrict__ invn, int n) {
  int wid = (blockIdx.x * blockDim.x + threadIdx.x) >> 6;
  int lane = threadIdx.x & 63;
  if (wid >= n) return;
  const float* hr = h + wid * HID;
  float s = 0.f;
  if (lane < HID) { float v = hr[lane]; s = v * v; }
  if (lane + 64 < HID) { float v = hr[lane + 64]; s = fmaf(v, v, s); }
#pragma unroll
  for (int off = 32; off; off >>= 1) s += __shfl_xor(s, off);
  if (lane == 0) invn[wid] = 1.f / fmaxf(sqrtf(s), 1e-12f);
}

// --------------------------------------------------------- in-degree histogram
__global__ __launch_bounds__(256) void hist_kernel(
    const int* __restrict__ ei, int* __restrict__ deg) {
  int e = blockIdx.x * blockDim.x + threadIdx.x;
  if (e >= E_TOT) return;
  int dst = (e < E_BASE) ? ei[E_BASE + e] : (e - E_BASE);
  atomicAdd(&deg[dst], 1);
}

// ------------------------------------------- hierarchical scan: block partials
__global__ __launch_bounds__(256) void scan_blocks_kernel(
    const int* __restrict__ deg, int* __restrict__ blocksum) {
  __shared__ int sh[4];
  int idx = blockIdx.x * 256 + threadIdx.x;
  int v = (idx < N_NODES) ? deg[idx] : 0;
#pragma unroll
  for (int off = 32; off; off >>= 1) v += __shfl_xor(v, off);
  if ((threadIdx.x & 63) == 0) sh[threadIdx.x >> 6] = v;
  __syncthreads();
  if (threadIdx.x == 0) blocksum[blockIdx.x] = sh[0] + sh[1] + sh[2] + sh[3];
}

// -------------------------------- hierarchical scan: 1-block scan of partials
__global__ __launch_bounds__(256) void scan_top_kernel(int* __restrict__ blocksum) {
  __shared__ int sh[256];
  int t = threadIdx.x;
  sh[t] = (t < SCAN_BLOCKS) ? blocksum[t] : 0;
  __syncthreads();
  for (int off = 1; off < 256; off <<= 1) {
    int v = (t >= off) ? sh[t - off] : 0;
    __syncthreads();
    sh[t] += v;
    __syncthreads();
  }
  if (t < SCAN_BLOCKS) blocksum[t] = (t == 0) ? 0 : sh[t - 1];  // exclusive, in place
}

// ------------------------- hierarchical scan: in-block scan + offset, fills cur
__global__ __launch_bounds__(256) void scan_apply_kernel(
    const int* __restrict__ deg, const int* __restrict__ blockoff,
    int* __restrict__ rowstart, int* __restrict__ cur) {
  __shared__ int sh[256];
  int t = threadIdx.x;
  int idx = blockIdx.x * 256 + t;
  int v = (idx < N_NODES) ? deg[idx] : 0;
  sh[t] = v;
  __syncthreads();
  for (int off = 1; off < 256; off <<= 1) {
    int u = (t >= off) ? sh[t - off] : 0;
    __syncthreads();
    sh[t] += u;
    __syncthreads();
  }
  int excl = blockoff[blockIdx.x] + sh[t] - v;
  if (idx < N_NODES) { rowstart[idx] = excl; cur[idx] = excl; }
  if (idx == N_NODES - 1) rowstart[N_NODES] = excl + v;
}

// --------------------------------------------------- scatter edges into CSR
__global__ __launch_bounds__(256) void scatter_kernel(
    const int* __restrict__ ei, int* __restrict__ cur,
    int* __restrict__ src_csr, int* __restrict__ dst_csr) {
  int e = blockIdx.x * blockDim.x + threadIdx.x;
  if (e >= E_TOT) return;
  int src, dst;
  if (e < E_BASE) { src = ei[e]; dst = ei[E_BASE + e]; }
  else            { src = dst = e - E_BASE; }
  int p = atomicAdd(&cur[dst], 1);
  src_csr[p] = src;
  dst_csr[p] = dst;
}

// ------------------------------------- per-edge attention logit (16 lanes/edge)
__global__ __launch_bounds__(256) void alpha_kernel(
    const float* __restrict__ h, const float* __restrict__ invn,
    const int* __restrict__ src_csr, const int* __restrict__ dst_csr,
    float* __restrict__ alpha, const float* __restrict__ beta_ptr) {
  int g = (blockIdx.x * 256 + threadIdx.x) >> 4;
  int l = threadIdx.x & 15;
  if (g >= E_TOT) return;
  int s = src_csr[g], d = dst_csr[g];
  const float* hs = h + s * HID;
  const float* hd = h + d * HID;
  float acc = 0.f;
  for (int k = l; k < HID; k += 16) acc = fmaf(hs[k], hd[k], acc);
#pragma unroll
  for (int off = 8; off; off >>= 1) acc += __shfl_xor(acc, off);
  if (l == 0) {
    float beta = beta_ptr ? beta_ptr[0] : 1.0f;
    alpha[g] = beta * acc * invn[s] * invn[d];
  }
}

// -------- per-node softmax + weighted aggregation: ONE WAVE per node, no LDS
__global__ __launch_bounds__(256) void agg_kernel(
    const float* __restrict__ h, const float* __restrict__ alpha,
    const int* __restrict__ src_csr, const int* __restrict__ rowstart,
    float* __restrict__ out) {
  int node = (blockIdx.x * 256 + threadIdx.x) >> 6;
  int lane = threadIdx.x & 63;
  if (node >= N_NODES) return;
  int start = rowstart[node], end = rowstart[node + 1];
  // segment max (coalesced over lanes)
  float m = -1e30f;
  for (int p = start + lane; p < end; p += 64) m = fmaxf(m, alpha[p]);
#pragma unroll
  for (int off = 32; off; off >>= 1) m = fmaxf(m, __shfl_xor(m, off));
  // segment sum of exp
  float s = 0.f;
  for (int p = start + lane; p < end; p += 64) s += __expf(alpha[p] - m);
#pragma unroll
  for (int off = 32; off; off >>= 1) s += __shfl_xor(s, off);
  float invden = 1.f / (s + 1e-16f);
  // weighted aggregation: edge loop serial, alpha/src wave-uniform broadcasts
  float acc0 = 0.f, acc1 = 0.f;
  for (int p = start; p < end; ++p) {
    float w = __expf(alpha[p] - m) * invden;
    int srcn = src_csr[p];
    const float* hr = h + (size_t)srcn * HID;
    acc0 = fmaf(w, hr[lane], acc0);
    if (lane < HID - 64) acc1 = fmaf(w, hr[lane + 64], acc1);
  }
  out[(size_t)node * HID + lane] = acc0;
  if (lane < HID - 64) out[(size_t)node * HID + 64 + lane] = acc1;
}

// ------------------------------------------------------------------ final lin2
__global__ __launch_bounds__(256) void lin2_kernel(
    const float* __restrict__ h, const float* __restrict__ w2,
    const float* __restrict__ b2, float* __restrict__ out, int n) {
  int wid = (blockIdx.x * blockDim.x + threadIdx.x) >> 6;
  int lane = threadIdx.x & 63;
  if (wid >= n) return;
  const float* hr = h + wid * HID;
  float s = 0.f;
  if (lane < HID) s = hr[lane] * w2[lane];
  if (lane + 64 < HID) s = fmaf(hr[lane + 64], w2[lane + 64], s);
#pragma unroll
  for (int off = 32; off; off >>= 1) s += __shfl_xor(s, off);
  if (lane == 0) out[wid] = s + b2[0];
}

extern "C" void kernel_launch(void* const* d_in, const int* in_sizes, int n_in,
                              void* d_out, int out_size, void* d_ws, size_t ws_size,
                              hipStream_t stream) {
  const float* x      = (const float*)d_in[0];
  const int*   ei     = (const int*)d_in[1];     // [2][E_BASE], int32
  const float* lin1_w = (const float*)d_in[2];
  const float* lin1_b = (const float*)d_in[3];
  const float* beta2  = (const float*)d_in[4];
  const float* lin2_w = (const float*)d_in[5];
  const float* lin2_b = (const float*)d_in[6];
  float* out = (float*)d_out;

  // workspace layout (all 4B elems)
  float* ws = (float*)d_ws;
  size_t off = 0;
  float* h1    = ws + off; off += (size_t)N_NODES * HID;
  float* h2    = ws + off; off += (size_t)N_NODES * HID;
  float* invn  = ws + off; off += N_NODES;
  float* alpha = ws + off; off += E_TOT;
  int* iws      = (int*)(ws + off);
  int* deg      = iws;                     // N
  int* rowstart = deg + N_NODES;           // N+1
  int* cur      = rowstart + N_NODES + 1;  // N
  int* src_csr  = cur + N_NODES;           // E_TOT
  int* dst_csr  = src_csr + E_TOT;         // E_TOT
  int* blocksum = dst_csr + E_TOT;         // SCAN_BLOCKS

  // ---- lin1 + relu
  lin1_kernel<<<(N_NODES * HID + 255) / 256, 256, 0, stream>>>(x, lin1_w, lin1_b, h1);

  // ---- build CSR by dst (reused by both props)
  hipMemsetAsync(deg, 0, N_NODES * sizeof(int), stream);
  hist_kernel<<<(E_TOT + 255) / 256, 256, 0, stream>>>(ei, deg);
  scan_blocks_kernel<<<SCAN_BLOCKS, 256, 0, stream>>>(deg, blocksum);
  scan_top_kernel<<<1, 256, 0, stream>>>(blocksum);
  scan_apply_kernel<<<SCAN_BLOCKS, 256, 0, stream>>>(deg, blocksum, rowstart, cur);
  scatter_kernel<<<(E_TOT + 255) / 256, 256, 0, stream>>>(ei, cur, src_csr, dst_csr);

  // ---- prop 1 (beta = 1.0)
  invnorm_kernel<<<(N_NODES + 3) / 4, 256, 0, stream>>>(h1, invn, N_NODES);
  alpha_kernel<<<(E_TOT + 15) / 16, 256, 0, stream>>>(h1, invn, src_csr, dst_csr, alpha, nullptr);
  agg_kernel<<<(N_NODES + 3) / 4, 256, 0, stream>>>(h1, alpha, src_csr, rowstart, h2);

  // ---- prop 2 (beta = beta2[0])
  invnorm_kernel<<<(N_NODES + 3) / 4, 256, 0, stream>>>(h2, invn, N_NODES);
  alpha_kernel<<<(E_TOT + 15) / 16, 256, 0, stream>>>(h2, invn, src_csr, dst_csr, alpha, beta2);
  agg_kernel<<<(N_NODES + 3) / 4, 256, 0, stream>>>(h2, alpha, src_csr, rowstart, h1);

  // ---- lin2
  lin2_kernel<<<(N_NODES + 3) / 4, 256, 0, stream>>>(h1, lin2_w, lin2_b, out, N_NODES);
}

// Round 3
// 385.567 us; speedup vs baseline: 1.7133x; 1.6648x over previous
//
#include <hip/hip_runtime.h>
#include <hip/hip_bf16.h>

#define N_NODES 50000
#define E_BASE  800000
#define E_TOT   850000   // + self loops
#define IN_DIM  58
#define HID     100
#define SCAN_BLOCKS ((N_NODES + 255) / 256)   // 196

// ---------------------------------------------------------------- lin1 + relu
__global__ __launch_bounds__(256) void lin1_kernel(
    const float* __restrict__ x, const float* __restrict__ w,
    const float* __restrict__ b, float* __restrict__ h) {
  __shared__ float wl[IN_DIM * HID];  // [k][j] layout
  __shared__ float bl[HID];
  int tid = threadIdx.x;
  for (int i = tid; i < IN_DIM * HID; i += 256) {
    int j = i / IN_DIM, k = i - j * IN_DIM;   // w row-major [j][k]
    wl[k * HID + j] = w[i];
  }
  if (tid < HID) bl[tid] = b[tid];
  __syncthreads();
  int idx = blockIdx.x * 256 + tid;
  if (idx >= N_NODES * HID) return;
  int n = idx / HID, j = idx - n * HID;
  const float* xr = x + n * IN_DIM;
  float acc = bl[j];
#pragma unroll
  for (int k = 0; k < IN_DIM; ++k) acc = fmaf(xr[k], wl[k * HID + j], acc);
  h[idx] = fmaxf(acc, 0.f);
}

// ------------------------------------------------------- per-row inverse norm
__global__ __launch_bounds__(256) void invnorm_kernel(
    const float* __restrict__ h, float* __restrict__ invn, int n) {
  int wid = (blockIdx.x * blockDim.x + threadIdx.x) >> 6;
  int lane = threadIdx.x & 63;
  if (wid >= n) return;
  const float* hr = h + wid * HID;
  float s = 0.f;
  { float v = hr[lane]; s = v * v; }
  if (lane < HID - 64) { float v = hr[lane + 64]; s = fmaf(v, v, s); }
#pragma unroll
  for (int off = 32; off; off >>= 1) s += __shfl_xor(s, off);
  if (lane == 0) invn[wid] = 1.f / fmaxf(sqrtf(s), 1e-12f);
}

// --------------------------------------------------------- in-degree histogram
__global__ __launch_bounds__(256) void hist_kernel(
    const int* __restrict__ ei, int* __restrict__ deg) {
  int e = blockIdx.x * blockDim.x + threadIdx.x;
  if (e >= E_TOT) return;
  int dst = (e < E_BASE) ? ei[E_BASE + e] : (e - E_BASE);
  atomicAdd(&deg[dst], 1);
}

// ------------------------------------------- hierarchical scan: block partials
__global__ __launch_bounds__(256) void scan_blocks_kernel(
    const int* __restrict__ deg, int* __restrict__ blocksum) {
  __shared__ int sh[4];
  int idx = blockIdx.x * 256 + threadIdx.x;
  int v = (idx < N_NODES) ? deg[idx] : 0;
#pragma unroll
  for (int off = 32; off; off >>= 1) v += __shfl_xor(v, off);
  if ((threadIdx.x & 63) == 0) sh[threadIdx.x >> 6] = v;
  __syncthreads();
  if (threadIdx.x == 0) blocksum[blockIdx.x] = sh[0] + sh[1] + sh[2] + sh[3];
}

// -------------------------------- hierarchical scan: 1-block scan of partials
__global__ __launch_bounds__(256) void scan_top_kernel(int* __restrict__ blocksum) {
  __shared__ int sh[256];
  int t = threadIdx.x;
  sh[t] = (t < SCAN_BLOCKS) ? blocksum[t] : 0;
  __syncthreads();
  for (int off = 1; off < 256; off <<= 1) {
    int v = (t >= off) ? sh[t - off] : 0;
    __syncthreads();
    sh[t] += v;
    __syncthreads();
  }
  if (t < SCAN_BLOCKS) blocksum[t] = (t == 0) ? 0 : sh[t - 1];  // exclusive, in place
}

// ------------------------- hierarchical scan: in-block scan + offset, fills cur
__global__ __launch_bounds__(256) void scan_apply_kernel(
    const int* __restrict__ deg, const int* __restrict__ blockoff,
    int* __restrict__ rowstart, int* __restrict__ cur) {
  __shared__ int sh[256];
  int t = threadIdx.x;
  int idx = blockIdx.x * 256 + t;
  int v = (idx < N_NODES) ? deg[idx] : 0;
  sh[t] = v;
  __syncthreads();
  for (int off = 1; off < 256; off <<= 1) {
    int u = (t >= off) ? sh[t - off] : 0;
    __syncthreads();
    sh[t] += u;
    __syncthreads();
  }
  int excl = blockoff[blockIdx.x] + sh[t] - v;
  if (idx < N_NODES) { rowstart[idx] = excl; cur[idx] = excl; }
  if (idx == N_NODES - 1) rowstart[N_NODES] = excl + v;
}

// --------------------------------------------------- scatter edges into CSR
__global__ __launch_bounds__(256) void scatter_kernel(
    const int* __restrict__ ei, int* __restrict__ cur,
    int* __restrict__ src_csr) {
  int e = blockIdx.x * blockDim.x + threadIdx.x;
  if (e >= E_TOT) return;
  int src, dst;
  if (e < E_BASE) { src = ei[e]; dst = ei[E_BASE + e]; }
  else            { src = dst = e - E_BASE; }
  int p = atomicAdd(&cur[dst], 1);
  src_csr[p] = src;
}

// ---------------------------------------------------------------- fused prop
// One wave per node. Online (flash-style) softmax: per edge load the src row
// ONCE, dot it against the invn-scaled dst row held in registers, update
// running (max, sum, weighted-acc) — no alpha array, no second gather pass.
// WRITE_INVN: emit invnorm of the output row (feeds the next prop).
// FINAL: skip feature write; apply lin2 (dot w2 + b2) in-register instead.
#define ONLINE_UPDATE(a_, v0_, v1_)                                   \
  {                                                                   \
    float a = (a_);                                                   \
    if (a > m) {                                                      \
      float r = __expf(m - a);                                        \
      m = a; s *= r; acc0 *= r; acc1 *= r;                            \
    }                                                                 \
    float wgt = __expf(a - m);                                        \
    s += wgt;                                                         \
    acc0 = fmaf(wgt, (v0_), acc0);                                    \
    acc1 = fmaf(wgt, (v1_), acc1);                                    \
  }

template<bool WRITE_INVN, bool FINAL>
__global__ __launch_bounds__(256) void prop_kernel(
    const float* __restrict__ h, const float* __restrict__ invn,
    const int* __restrict__ src_csr, const int* __restrict__ rowstart,
    const float* __restrict__ beta_ptr,
    float* __restrict__ out_feat, float* __restrict__ out_invn,
    const float* __restrict__ w2, const float* __restrict__ b2,
    float* __restrict__ out_scalar) {
  int node = (blockIdx.x * 256 + threadIdx.x) >> 6;
  int lane = threadIdx.x & 63;
  if (node >= N_NODES) return;
  const bool hi = lane < (HID - 64);   // lanes holding the second feature chunk
  float beta = beta_ptr ? beta_ptr[0] : 1.0f;
  int start = rowstart[node], end = rowstart[node + 1];
  const float* hd = h + (size_t)node * HID;
  float ind = invn[node];
  float d0 = hd[lane] * ind;
  float d1 = hi ? hd[lane + 64] * ind : 0.f;
  float m = -1e30f, s = 0.f, acc0 = 0.f, acc1 = 0.f;
  int p = start;
  for (; p + 3 < end; p += 4) {
    // issue 4 edges' loads together (independent -> pipelined)
    int sn0 = src_csr[p],     sn1 = src_csr[p + 1];
    int sn2 = src_csr[p + 2], sn3 = src_csr[p + 3];
    float i0 = invn[sn0], i1 = invn[sn1], i2 = invn[sn2], i3 = invn[sn3];
    const float* r0 = h + (size_t)sn0 * HID;
    const float* r1 = h + (size_t)sn1 * HID;
    const float* r2 = h + (size_t)sn2 * HID;
    const float* r3 = h + (size_t)sn3 * HID;
    float v00 = r0[lane], v01 = hi ? r0[lane + 64] : 0.f;
    float v10 = r1[lane], v11 = hi ? r1[lane + 64] : 0.f;
    float v20 = r2[lane], v21 = hi ? r2[lane + 64] : 0.f;
    float v30 = r3[lane], v31 = hi ? r3[lane + 64] : 0.f;
    float t0 = fmaf(v01, d1, v00 * d0);
    float t1 = fmaf(v11, d1, v10 * d0);
    float t2 = fmaf(v21, d1, v20 * d0);
    float t3 = fmaf(v31, d1, v30 * d0);
    // 4 interleaved reduce trees hide shfl latency
#pragma unroll
    for (int off = 32; off; off >>= 1) {
      t0 += __shfl_xor(t0, off);
      t1 += __shfl_xor(t1, off);
      t2 += __shfl_xor(t2, off);
      t3 += __shfl_xor(t3, off);
    }
    ONLINE_UPDATE(beta * t0 * i0, v00, v01);
    ONLINE_UPDATE(beta * t1 * i1, v10, v11);
    ONLINE_UPDATE(beta * t2 * i2, v20, v21);
    ONLINE_UPDATE(beta * t3 * i3, v30, v31);
  }
  for (; p < end; ++p) {
    int sn = src_csr[p];
    float iv = invn[sn];
    const float* r = h + (size_t)sn * HID;
    float v0 = r[lane], v1 = hi ? r[lane + 64] : 0.f;
    float t = fmaf(v1, d1, v0 * d0);
#pragma unroll
    for (int off = 32; off; off >>= 1) t += __shfl_xor(t, off);
    ONLINE_UPDATE(beta * t * iv, v0, v1);
  }
  float invden = 1.f / (s + 1e-16f);
  float o0 = acc0 * invden, o1 = acc1 * invden;
  if (!FINAL) {
    out_feat[(size_t)node * HID + lane] = o0;
    if (hi) out_feat[(size_t)node * HID + 64 + lane] = o1;
  }
  if (WRITE_INVN) {
    float q = fmaf(o0, o0, o1 * o1);   // o1 == 0 for !hi lanes
#pragma unroll
    for (int off = 32; off; off >>= 1) q += __shfl_xor(q, off);
    if (lane == 0) out_invn[node] = 1.f / fmaxf(sqrtf(q), 1e-12f);
  }
  if (FINAL) {
    float q = o0 * w2[lane];
    if (hi) q = fmaf(o1, w2[lane + 64], q);
#pragma unroll
    for (int off = 32; off; off >>= 1) q += __shfl_xor(q, off);
    if (lane == 0) out_scalar[node] = q + b2[0];
  }
}

extern "C" void kernel_launch(void* const* d_in, const int* in_sizes, int n_in,
                              void* d_out, int out_size, void* d_ws, size_t ws_size,
                              hipStream_t stream) {
  const float* x      = (const float*)d_in[0];
  const int*   ei     = (const int*)d_in[1];     // [2][E_BASE], int32
  const float* lin1_w = (const float*)d_in[2];
  const float* lin1_b = (const float*)d_in[3];
  const float* beta2  = (const float*)d_in[4];
  const float* lin2_w = (const float*)d_in[5];
  const float* lin2_b = (const float*)d_in[6];
  float* out = (float*)d_out;

  // workspace layout (all 4B elems)
  float* ws = (float*)d_ws;
  size_t off = 0;
  float* h1    = ws + off; off += (size_t)N_NODES * HID;
  float* h2    = ws + off; off += (size_t)N_NODES * HID;
  float* invn1 = ws + off; off += N_NODES;
  float* invn2 = ws + off; off += N_NODES;
  int* iws      = (int*)(ws + off);
  int* deg      = iws;                     // N
  int* rowstart = deg + N_NODES;           // N+1
  int* cur      = rowstart + N_NODES + 1;  // N
  int* src_csr  = cur + N_NODES;           // E_TOT
  int* blocksum = src_csr + E_TOT;         // SCAN_BLOCKS

  // ---- lin1 + relu
  lin1_kernel<<<(N_NODES * HID + 255) / 256, 256, 0, stream>>>(x, lin1_w, lin1_b, h1);

  // ---- build CSR by dst (reused by both props)
  hipMemsetAsync(deg, 0, N_NODES * sizeof(int), stream);
  hist_kernel<<<(E_TOT + 255) / 256, 256, 0, stream>>>(ei, deg);
  scan_blocks_kernel<<<SCAN_BLOCKS, 256, 0, stream>>>(deg, blocksum);
  scan_top_kernel<<<1, 256, 0, stream>>>(blocksum);
  scan_apply_kernel<<<SCAN_BLOCKS, 256, 0, stream>>>(deg, blocksum, rowstart, cur);
  scatter_kernel<<<(E_TOT + 255) / 256, 256, 0, stream>>>(ei, cur, src_csr);

  // ---- invnorm of h1
  invnorm_kernel<<<(N_NODES + 3) / 4, 256, 0, stream>>>(h1, invn1, N_NODES);

  // ---- prop 1 (beta = 1.0): h1 -> h2, also produce invn2
  prop_kernel<true, false><<<(N_NODES + 3) / 4, 256, 0, stream>>>(
      h1, invn1, src_csr, rowstart, nullptr, h2, invn2, nullptr, nullptr, nullptr);

  // ---- prop 2 (beta = beta2[0]) fused with lin2: h2 -> out (scalar per node)
  prop_kernel<false, true><<<(N_NODES + 3) / 4, 256, 0, stream>>>(
      h2, invn2, src_csr, rowstart, beta2, nullptr, nullptr, lin2_w, lin2_b, out);
}

// Round 4
// 332.445 us; speedup vs baseline: 1.9871x; 1.1598x over previous
//
#include <hip/hip_runtime.h>
#include <hip/hip_bf16.h>

#define N_NODES 50000
#define E_BASE  800000
#define E_TOT   850000   // + self loops
#define IN_DIM  58
#define HID     100
#define HP      112      // padded feature stride = 16 lanes x 7
#define SCAN_BLOCKS ((N_NODES + 255) / 256)   // 196

// ---------------- lin1 + relu: 64 nodes x 112 cols / block, 4n x 7f reg tile
__global__ __launch_bounds__(256) void lin1_kernel(
    const float* __restrict__ x, const float* __restrict__ w,
    const float* __restrict__ b, float* __restrict__ h) {
  __shared__ float xs[IN_DIM * 64];    // [k][n]
  __shared__ float wsm[IN_DIM * HP];   // [k][j], cols >=100 zero
  __shared__ float bl[HP];
  int tid = threadIdx.x;
  int nb = blockIdx.x * 64;
  for (int i = tid; i < 64 * IN_DIM; i += 256) {       // coalesced x stage
    int g = nb * IN_DIM + i;
    int n = i / IN_DIM, k = i - n * IN_DIM;
    xs[k * 64 + n] = (g < N_NODES * IN_DIM) ? x[g] : 0.f;
  }
  for (int i = tid; i < IN_DIM * HP; i += 256) {       // w transpose+pad stage
    int k = i / HP, j = i - k * HP;
    wsm[i] = (j < HID) ? w[j * IN_DIM + k] : 0.f;
  }
  if (tid < HP) bl[tid] = (tid < HID) ? b[tid] : 0.f;
  __syncthreads();
  int t_j = tid & 15, t_n = tid >> 4;
  float acc[4][7];
#pragma unroll
  for (int ni = 0; ni < 4; ++ni)
#pragma unroll
    for (int j = 0; j < 7; ++j) acc[ni][j] = bl[t_j + 16 * j];
  for (int k = 0; k < IN_DIM; ++k) {
    float4 xv = *reinterpret_cast<const float4*>(&xs[k * 64 + 4 * t_n]);
    float wv[7];
#pragma unroll
    for (int j = 0; j < 7; ++j) wv[j] = wsm[k * HP + t_j + 16 * j];
#pragma unroll
    for (int j = 0; j < 7; ++j) {
      acc[0][j] = fmaf(xv.x, wv[j], acc[0][j]);
      acc[1][j] = fmaf(xv.y, wv[j], acc[1][j]);
      acc[2][j] = fmaf(xv.z, wv[j], acc[2][j]);
      acc[3][j] = fmaf(xv.w, wv[j], acc[3][j]);
    }
  }
#pragma unroll
  for (int ni = 0; ni < 4; ++ni) {
    int n = nb + 4 * t_n + ni;
    if (n < N_NODES) {
#pragma unroll
      for (int j = 0; j < 7; ++j)
        h[(size_t)n * HP + t_j + 16 * j] = fmaxf(acc[ni][j], 0.f);  // pads -> 0
    }
  }
}

// ------------------------------------------------------- per-row inverse norm
__global__ __launch_bounds__(256) void invnorm_kernel(
    const float* __restrict__ h, float* __restrict__ invn, int n) {
  int wid = (blockIdx.x * blockDim.x + threadIdx.x) >> 6;
  int lane = threadIdx.x & 63;
  if (wid >= n) return;
  const float* hr = h + (size_t)wid * HP;
  float v0 = hr[lane];
  float s = v0 * v0;
  if (lane < HP - 64) { float v1 = hr[lane + 64]; s = fmaf(v1, v1, s); }
#pragma unroll
  for (int off = 32; off; off >>= 1) s += __shfl_xor(s, off);
  if (lane == 0) invn[wid] = 1.f / fmaxf(sqrtf(s), 1e-12f);
}

// --------------------------------------------------------- in-degree histogram
__global__ __launch_bounds__(256) void hist_kernel(
    const int* __restrict__ ei, int* __restrict__ deg) {
  int e = blockIdx.x * blockDim.x + threadIdx.x;
  if (e >= E_TOT) return;
  int dst = (e < E_BASE) ? ei[E_BASE + e] : (e - E_BASE);
  atomicAdd(&deg[dst], 1);
}

// ------------------------------------------- hierarchical scan: block partials
__global__ __launch_bounds__(256) void scan_blocks_kernel(
    const int* __restrict__ deg, int* __restrict__ blocksum) {
  __shared__ int sh[4];
  int idx = blockIdx.x * 256 + threadIdx.x;
  int v = (idx < N_NODES) ? deg[idx] : 0;
#pragma unroll
  for (int off = 32; off; off >>= 1) v += __shfl_xor(v, off);
  if ((threadIdx.x & 63) == 0) sh[threadIdx.x >> 6] = v;
  __syncthreads();
  if (threadIdx.x == 0) blocksum[blockIdx.x] = sh[0] + sh[1] + sh[2] + sh[3];
}

// -------------------------------- hierarchical scan: 1-block scan of partials
__global__ __launch_bounds__(256) void scan_top_kernel(int* __restrict__ blocksum) {
  __shared__ int sh[256];
  int t = threadIdx.x;
  sh[t] = (t < SCAN_BLOCKS) ? blocksum[t] : 0;
  __syncthreads();
  for (int off = 1; off < 256; off <<= 1) {
    int v = (t >= off) ? sh[t - off] : 0;
    __syncthreads();
    sh[t] += v;
    __syncthreads();
  }
  if (t < SCAN_BLOCKS) blocksum[t] = (t == 0) ? 0 : sh[t - 1];  // exclusive
}

// ------------------------- hierarchical scan: in-block scan + offset, fills cur
__global__ __launch_bounds__(256) void scan_apply_kernel(
    const int* __restrict__ deg, const int* __restrict__ blockoff,
    int* __restrict__ rowstart, int* __restrict__ cur) {
  __shared__ int sh[256];
  int t = threadIdx.x;
  int idx = blockIdx.x * 256 + t;
  int v = (idx < N_NODES) ? deg[idx] : 0;
  sh[t] = v;
  __syncthreads();
  for (int off = 1; off < 256; off <<= 1) {
    int u = (t >= off) ? sh[t - off] : 0;
    __syncthreads();
    sh[t] += u;
    __syncthreads();
  }
  int excl = blockoff[blockIdx.x] + sh[t] - v;
  if (idx < N_NODES) { rowstart[idx] = excl; cur[idx] = excl; }
  if (idx == N_NODES - 1) rowstart[N_NODES] = excl + v;
}

// --------------------------------------------------- scatter edges into CSR
__global__ __launch_bounds__(256) void scatter_kernel(
    const int* __restrict__ ei, int* __restrict__ cur,
    int* __restrict__ src_csr) {
  int e = blockIdx.x * blockDim.x + threadIdx.x;
  if (e >= E_TOT) return;
  int src, dst;
  if (e < E_BASE) { src = ei[e]; dst = ei[E_BASE + e]; }
  else            { src = dst = e - E_BASE; }
  int p = atomicAdd(&cur[dst], 1);
  src_csr[p] = src;
}

// ---------------------------------------------------------------- fused prop
// One wave per node; 4 edges processed in parallel by 16-lane quarters, each
// quarter holding its own online-softmax state (m, s, acc[7]); states merged
// at the end flash-style via 2 shfl_xor levels. Branchless online update.
// Feature f = lq + 16*j (j<7), row stride HP=112, pad cols are zero.
template<bool WRITE_INVN, bool FINAL>
__global__ __launch_bounds__(256) void prop_kernel(
    const float* __restrict__ h, const float* __restrict__ invn,
    const int* __restrict__ src_csr, const int* __restrict__ rowstart,
    const float* __restrict__ beta_ptr,
    float* __restrict__ out_feat, float* __restrict__ out_invn,
    const float* __restrict__ w2, const float* __restrict__ b2,
    float* __restrict__ out_scalar) {
  int node = (blockIdx.x * 256 + threadIdx.x) >> 6;
  int lane = threadIdx.x & 63;
  if (node >= N_NODES) return;
  int lq = lane & 15, q = lane >> 4;
  float beta = beta_ptr ? beta_ptr[0] : 1.0f;
  int start = rowstart[node], end = rowstart[node + 1];
  int deg = end - start;             // >= 1 (self loop)
  const float* hd = h + (size_t)node * HP;
  float ind = invn[node];
  float d[7];
#pragma unroll
  for (int j = 0; j < 7; ++j) d[j] = hd[lq + 16 * j] * ind;
  float m = -1e30f, s = 0.f;
  float acc[7];
#pragma unroll
  for (int j = 0; j < 7; ++j) acc[j] = 0.f;
  int nt = (deg + 3) >> 2;
  for (int r = 0; r < nt; ++r) {
    int e = 4 * r + q;
    bool valid = e < deg;
    int p = start + (valid ? e : 0);
    int sn = src_csr[p];
    float iv = invn[sn];
    const float* hs = h + (size_t)sn * HP;
    float v[7];
#pragma unroll
    for (int j = 0; j < 7; ++j) v[j] = hs[lq + 16 * j];
    float t = 0.f;
#pragma unroll
    for (int j = 0; j < 7; ++j) t = fmaf(v[j], d[j], t);
#pragma unroll
    for (int off = 8; off; off >>= 1) t += __shfl_xor(t, off);
    float a = valid ? beta * t * iv : -1e30f;
    float nm = fmaxf(m, a);
    float rr = __expf(m - nm);       // 1 if no new max; 0-ish if first edge
    float wgt = __expf(a - nm);      // 0 for invalid quarters
    s = fmaf(s, rr, wgt);
    m = nm;
#pragma unroll
    for (int j = 0; j < 7; ++j) acc[j] = fmaf(acc[j], rr, wgt * v[j]);
  }
  // merge the 4 quarter states (each uniform within its quarter)
#pragma unroll
  for (int off = 16; off <= 32; off <<= 1) {
    float m2 = __shfl_xor(m, off);
    float s2 = __shfl_xor(s, off);
    float nm = fmaxf(m, m2);
    float r1 = __expf(m - nm), r2 = __expf(m2 - nm);
    s = s * r1 + s2 * r2;
#pragma unroll
    for (int j = 0; j < 7; ++j) {
      float a2 = __shfl_xor(acc[j], off);
      acc[j] = acc[j] * r1 + a2 * r2;
    }
    m = nm;
  }
  float invden = 1.f / (s + 1e-16f);
  float o[7];
#pragma unroll
  for (int j = 0; j < 7; ++j) o[j] = acc[j] * invden;
  if (!FINAL) {
    if (q == 0) {
#pragma unroll
      for (int j = 0; j < 7; ++j)
        out_feat[(size_t)node * HP + lq + 16 * j] = o[j];   // pads stay 0
    }
    if (WRITE_INVN) {
      float qq = 0.f;
#pragma unroll
      for (int j = 0; j < 7; ++j) qq = fmaf(o[j], o[j], qq);
#pragma unroll
      for (int off = 8; off; off >>= 1) qq += __shfl_xor(qq, off);
      if (lane == 0) out_invn[node] = 1.f / fmaxf(sqrtf(qq), 1e-12f);
    }
  } else {
    float qq = 0.f;
#pragma unroll
    for (int j = 0; j < 7; ++j) {
      int f = lq + 16 * j;
      float wv = (f < HID) ? w2[f] : 0.f;
      qq = fmaf(o[j], wv, qq);
    }
#pragma unroll
    for (int off = 8; off; off >>= 1) qq += __shfl_xor(qq, off);
    if (lane == 0) out_scalar[node] = qq + b2[0];
  }
}

extern "C" void kernel_launch(void* const* d_in, const int* in_sizes, int n_in,
                              void* d_out, int out_size, void* d_ws, size_t ws_size,
                              hipStream_t stream) {
  const float* x      = (const float*)d_in[0];
  const int*   ei     = (const int*)d_in[1];     // [2][E_BASE], int32
  const float* lin1_w = (const float*)d_in[2];
  const float* lin1_b = (const float*)d_in[3];
  const float* beta2  = (const float*)d_in[4];
  const float* lin2_w = (const float*)d_in[5];
  const float* lin2_b = (const float*)d_in[6];
  float* out = (float*)d_out;

  // workspace layout (all 4B elems)
  float* ws = (float*)d_ws;
  size_t off = 0;
  float* h1    = ws + off; off += (size_t)N_NODES * HP;
  float* h2    = ws + off; off += (size_t)N_NODES * HP;
  float* invn1 = ws + off; off += N_NODES;
  float* invn2 = ws + off; off += N_NODES;
  int* iws      = (int*)(ws + off);
  int* deg      = iws;                     // N
  int* rowstart = deg + N_NODES;           // N+1
  int* cur      = rowstart + N_NODES + 1;  // N
  int* src_csr  = cur + N_NODES;           // E_TOT
  int* blocksum = src_csr + E_TOT;         // SCAN_BLOCKS

  // ---- lin1 + relu (writes padded rows, pad cols = 0)
  lin1_kernel<<<(N_NODES + 63) / 64, 256, 0, stream>>>(x, lin1_w, lin1_b, h1);

  // ---- build CSR by dst (reused by both props)
  hipMemsetAsync(deg, 0, N_NODES * sizeof(int), stream);
  hist_kernel<<<(E_TOT + 255) / 256, 256, 0, stream>>>(ei, deg);
  scan_blocks_kernel<<<SCAN_BLOCKS, 256, 0, stream>>>(deg, blocksum);
  scan_top_kernel<<<1, 256, 0, stream>>>(blocksum);
  scan_apply_kernel<<<SCAN_BLOCKS, 256, 0, stream>>>(deg, blocksum, rowstart, cur);
  scatter_kernel<<<(E_TOT + 255) / 256, 256, 0, stream>>>(ei, cur, src_csr);

  // ---- invnorm of h1
  invnorm_kernel<<<(N_NODES + 3) / 4, 256, 0, stream>>>(h1, invn1, N_NODES);

  // ---- prop 1 (beta = 1.0): h1 -> h2, also produce invn2
  prop_kernel<true, false><<<(N_NODES + 3) / 4, 256, 0, stream>>>(
      h1, invn1, src_csr, rowstart, nullptr, h2, invn2, nullptr, nullptr, nullptr);

  // ---- prop 2 (beta = beta2[0]) fused with lin2: h2 -> out (scalar per node)
  prop_kernel<false, true><<<(N_NODES + 3) / 4, 256, 0, stream>>>(
      h2, invn2, src_csr, rowstart, beta2, nullptr, nullptr, lin2_w, lin2_b, out);
}

// Round 9
// 300.694 us; speedup vs baseline: 2.1969x; 1.1056x over previous
//
#include <hip/hip_runtime.h>
#include <hip/hip_fp16.h>

#define N_NODES 50000
#define E_BASE  800000
#define IN_DIM  58
#define HID     100
#define HP2     128            // padded halves per feature row (256 B)
#define SCAN_BLOCKS ((N_NODES + 255) / 256)   // 196

// ---- lin1 + relu + fp16 quantize + fused invnorm (computed on quantized vals)
__global__ __launch_bounds__(256) void lin1_kernel(
    const float* __restrict__ x, const float* __restrict__ w,
    const float* __restrict__ b, __half* __restrict__ h,
    float* __restrict__ invn) {
  __shared__ alignas(16) float xs[64 * IN_DIM];    // [n][k] linear (no transpose)
  __shared__ alignas(16) float wsm[IN_DIM * HP2];  // [k][j], cols >=100 zero
  __shared__ float bl[HP2];
  int tid = threadIdx.x;
  int nb = blockIdx.x * 64;
  for (int i = tid; i < 64 * IN_DIM; i += 256) {   // coalesced, conflict-free
    int g = nb * IN_DIM + i;
    xs[i] = (g < N_NODES * IN_DIM) ? x[g] : 0.f;
  }
  for (int i = tid; i < IN_DIM * HP2; i += 256) {  // w transpose+pad stage
    int k = i / HP2, j = i - k * HP2;
    wsm[i] = (j < HID) ? w[j * IN_DIM + k] : 0.f;
  }
  if (tid < HP2) bl[tid] = (tid < HID) ? b[tid] : 0.f;
  __syncthreads();
  int t_j = tid & 15, t_n = tid >> 4;   // cols 8*t_j..+7 (contiguous), nodes 4*t_n..+3
  float acc[4][8];
#pragma unroll
  for (int ni = 0; ni < 4; ++ni)
#pragma unroll
    for (int j = 0; j < 8; ++j) acc[ni][j] = bl[8 * t_j + j];
  for (int k = 0; k < IN_DIM; ++k) {
    float xv[4];
#pragma unroll
    for (int ni = 0; ni < 4; ++ni) xv[ni] = xs[(4 * t_n + ni) * IN_DIM + k];
    float4 wa = *(const float4*)&wsm[k * HP2 + 8 * t_j];
    float4 wb = *(const float4*)&wsm[k * HP2 + 8 * t_j + 4];
    float wv[8] = {wa.x, wa.y, wa.z, wa.w, wb.x, wb.y, wb.z, wb.w};
#pragma unroll
    for (int ni = 0; ni < 4; ++ni)
#pragma unroll
      for (int j = 0; j < 8; ++j) acc[ni][j] = fmaf(xv[ni], wv[j], acc[ni][j]);
  }
#pragma unroll
  for (int ni = 0; ni < 4; ++ni) {
    int n = nb + 4 * t_n + ni;
    uint4 st;
    ushort* sp = (ushort*)&st;
    float ss = 0.f;
#pragma unroll
    for (int j = 0; j < 8; ++j) {
      float v = fmaxf(acc[ni][j], 0.f);
      __half hv = __float2half_rn(v);         // pad cols are exactly 0
      sp[j] = __half_as_ushort(hv);
      float vq = __half2float(hv);
      ss = fmaf(vq, vq, ss);
    }
#pragma unroll
    for (int off = 1; off < 16; off <<= 1) ss += __shfl_xor(ss, off);
    if (n < N_NODES) {
      *((uint4*)(h + (size_t)n * HP2) + t_j) = st;
      if (t_j == 0) invn[n] = 1.f / fmaxf(sqrtf(ss), 1e-12f);
    }
  }
}

// --------------------------------- in-degree histogram (base edges, 4/thread)
__global__ __launch_bounds__(256) void hist_kernel(
    const int* __restrict__ ei, int* __restrict__ deg) {
  int i = blockIdx.x * 256 + threadIdx.x;
  if (i >= E_BASE / 4) return;
  int4 d4 = ((const int4*)(ei + E_BASE))[i];
  atomicAdd(&deg[d4.x], 1);
  atomicAdd(&deg[d4.y], 1);
  atomicAdd(&deg[d4.z], 1);
  atomicAdd(&deg[d4.w], 1);
}

// ------------------------------------------- hierarchical scan: block partials
// counts are deg[idx]+1 (implicit self loop)
__global__ __launch_bounds__(256) void scan_blocks_kernel(
    const int* __restrict__ deg, int* __restrict__ blocksum) {
  __shared__ int sh[4];
  int idx = blockIdx.x * 256 + threadIdx.x;
  int v = (idx < N_NODES) ? deg[idx] + 1 : 0;
#pragma unroll
  for (int off = 32; off; off >>= 1) v += __shfl_xor(v, off);
  if ((threadIdx.x & 63) == 0) sh[threadIdx.x >> 6] = v;
  __syncthreads();
  if (threadIdx.x == 0) blocksum[blockIdx.x] = sh[0] + sh[1] + sh[2] + sh[3];
}

// -------------------------------- hierarchical scan: 1-block scan of partials
__global__ __launch_bounds__(256) void scan_top_kernel(int* __restrict__ blocksum) {
  __shared__ int sh[256];
  int t = threadIdx.x;
  sh[t] = (t < SCAN_BLOCKS) ? blocksum[t] : 0;
  __syncthreads();
  for (int off = 1; off < 256; off <<= 1) {
    int v = (t >= off) ? sh[t - off] : 0;
    __syncthreads();
    sh[t] += v;
    __syncthreads();
  }
  if (t < SCAN_BLOCKS) blocksum[t] = (t == 0) ? 0 : sh[t - 1];  // exclusive
}

// ---- scan apply: rowstart, cur (=start+1), and self-loop edge in slot 0
__global__ __launch_bounds__(256) void scan_apply_kernel(
    const int* __restrict__ deg, const int* __restrict__ blockoff,
    int* __restrict__ rowstart, int* __restrict__ cur,
    int* __restrict__ src_csr) {
  __shared__ int sh[256];
  int t = threadIdx.x;
  int idx = blockIdx.x * 256 + t;
  int v = (idx < N_NODES) ? deg[idx] + 1 : 0;
  sh[t] = v;
  __syncthreads();
  for (int off = 1; off < 256; off <<= 1) {
    int u = (t >= off) ? sh[t - off] : 0;
    __syncthreads();
    sh[t] += u;
    __syncthreads();
  }
  int excl = blockoff[blockIdx.x] + sh[t] - v;
  if (idx < N_NODES) {
    rowstart[idx] = excl;
    src_csr[excl] = idx;      // self loop occupies slot 0, no atomic
    cur[idx] = excl + 1;
  }
  if (idx == N_NODES - 1) rowstart[N_NODES] = excl + v;
}

// --------------------------------------- scatter base edges into CSR, 4/thread
__global__ __launch_bounds__(256) void scatter_kernel(
    const int* __restrict__ ei, int* __restrict__ cur,
    int* __restrict__ src_csr) {
  int i = blockIdx.x * 256 + threadIdx.x;
  if (i >= E_BASE / 4) return;
  int4 s4 = ((const int4*)ei)[i];
  int4 d4 = ((const int4*)(ei + E_BASE))[i];
  int p;
  p = atomicAdd(&cur[d4.x], 1); src_csr[p] = s4.x;
  p = atomicAdd(&cur[d4.y], 1); src_csr[p] = s4.y;
  p = atomicAdd(&cur[d4.z], 1); src_csr[p] = s4.z;
  p = atomicAdd(&cur[d4.w], 1); src_csr[p] = s4.w;
}

// ---------------------------------------------------------------- fused prop
// One wave per node; 4 edges in parallel (16-lane quarters). fp16 rows, one
// dwordx4 per lane per row. Softmax max is FIXED at B=|beta| (logits are
// beta*cos, bounded by |beta|) -> no online max, no rescale; quarter states
// merge by plain addition.
template<bool WRITE_INVN, bool FINAL>
__global__ __launch_bounds__(256) void prop_kernel(
    const __half* __restrict__ h, const float* __restrict__ invn,
    const int* __restrict__ src_csr, const int* __restrict__ rowstart,
    const float* __restrict__ beta_ptr,
    __half* __restrict__ out_feat, float* __restrict__ out_invn,
    const float* __restrict__ w2, const float* __restrict__ b2,
    float* __restrict__ out_scalar) {
  int node = (blockIdx.x * 256 + threadIdx.x) >> 6;
  int lane = threadIdx.x & 63;
  if (node >= N_NODES) return;
  int lq = lane & 15, q = lane >> 4;
  float beta = beta_ptr ? beta_ptr[0] : 1.0f;
  float B = fabsf(beta);
  int start = rowstart[node], end = rowstart[node + 1];
  int deg = end - start;               // >= 1 (self loop)
  float ind = invn[node];
  uint4 dv = *((const uint4*)(h + (size_t)node * HP2) + lq);
  const __half* dh = (const __half*)&dv;
  float d[8];
#pragma unroll
  for (int j = 0; j < 8; ++j) d[j] = __half2float(dh[j]) * ind;
  float s = 0.f;
  float acc[8];
#pragma unroll
  for (int j = 0; j < 8; ++j) acc[j] = 0.f;
  int nt = (deg + 3) >> 2;
  for (int r = 0; r < nt; ++r) {
    int e = 4 * r + q;
    bool valid = e < deg;
    int p = start + (valid ? e : 0);
    int sn = src_csr[p];
    float iv = invn[sn];
    uint4 vv = *((const uint4*)(h + (size_t)sn * HP2) + lq);
    const __half* vh = (const __half*)&vv;
    float vf[8];
#pragma unroll
    for (int j = 0; j < 8; ++j) vf[j] = __half2float(vh[j]);
    float t = 0.f;
#pragma unroll
    for (int j = 0; j < 8; ++j) t = fmaf(vf[j], d[j], t);
#pragma unroll
    for (int off = 8; off; off >>= 1) t += __shfl_xor(t, off);
    float a = valid ? beta * t * iv : -1e30f;
    float wgt = __expf(a - B);         // in (0, ~1]; 0 for invalid slots
    s += wgt;
#pragma unroll
    for (int j = 0; j < 8; ++j) acc[j] = fmaf(wgt, vf[j], acc[j]);
  }
  // merge the 4 quarter states: plain sums (shared fixed max B)
#pragma unroll
  for (int off = 16; off <= 32; off <<= 1) {
    s += __shfl_xor(s, off);
#pragma unroll
    for (int j = 0; j < 8; ++j) acc[j] += __shfl_xor(acc[j], off);
  }
  float invden = 1.f / (s + 1e-16f);
  if (!FINAL) {
    uint4 st;
    ushort* sp = (ushort*)&st;
    float ss = 0.f;
#pragma unroll
    for (int j = 0; j < 8; ++j) {
      __half hv = __float2half_rn(acc[j] * invden);
      sp[j] = __half_as_ushort(hv);
      float vq = __half2float(hv);
      ss = fmaf(vq, vq, ss);
    }
    if (q == 0) *((uint4*)(out_feat + (size_t)node * HP2) + lq) = st;
    if (WRITE_INVN) {
#pragma unroll
      for (int off = 1; off < 16; off <<= 1) ss += __shfl_xor(ss, off);
      if (lane == 0) out_invn[node] = 1.f / fmaxf(sqrtf(ss), 1e-12f);
    }
  } else {
    float qq = 0.f;
#pragma unroll
    for (int j = 0; j < 8; ++j) {
      int f = 8 * lq + j;
      float wv = (f < HID) ? w2[f] : 0.f;
      qq = fmaf(acc[j] * invden, wv, qq);
    }
#pragma unroll
    for (int off = 8; off; off >>= 1) qq += __shfl_xor(qq, off);
    if (lane == 0) out_scalar[node] = qq + b2[0];
  }
}

extern "C" void kernel_launch(void* const* d_in, const int* in_sizes, int n_in,
                              void* d_out, int out_size, void* d_ws, size_t ws_size,
                              hipStream_t stream) {
  const float* x      = (const float*)d_in[0];
  const int*   ei     = (const int*)d_in[1];     // [2][E_BASE], int32
  const float* lin1_w = (const float*)d_in[2];
  const float* lin1_b = (const float*)d_in[3];
  const float* beta2  = (const float*)d_in[4];
  const float* lin2_w = (const float*)d_in[5];
  const float* lin2_b = (const float*)d_in[6];
  float* out = (float*)d_out;

  // workspace layout
  char* wsb = (char*)d_ws;
  __half* h1 = (__half*)wsb;                       wsb += (size_t)N_NODES * HP2 * 2;
  __half* h2 = (__half*)wsb;                       wsb += (size_t)N_NODES * HP2 * 2;
  float* invn1 = (float*)wsb;                      wsb += N_NODES * 4;
  float* invn2 = (float*)wsb;                      wsb += N_NODES * 4;
  int* deg      = (int*)wsb;                       wsb += N_NODES * 4;
  int* rowstart = (int*)wsb;                       wsb += (N_NODES + 1) * 4;
  int* cur      = (int*)wsb;                       wsb += N_NODES * 4;
  int* src_csr  = (int*)wsb;                       wsb += (size_t)(E_BASE + N_NODES) * 4;
  int* blocksum = (int*)wsb;                       wsb += SCAN_BLOCKS * 4;

  // ---- lin1 + relu -> fp16 h1 + invn1 (fused)
  lin1_kernel<<<(N_NODES + 63) / 64, 256, 0, stream>>>(x, lin1_w, lin1_b, h1, invn1);

  // ---- build CSR by dst (self loop in slot 0 of each row, no atomics for it)
  hipMemsetAsync(deg, 0, N_NODES * sizeof(int), stream);
  hist_kernel<<<(E_BASE / 4 + 255) / 256, 256, 0, stream>>>(ei, deg);
  scan_blocks_kernel<<<SCAN_BLOCKS, 256, 0, stream>>>(deg, blocksum);
  scan_top_kernel<<<1, 256, 0, stream>>>(blocksum);
  scan_apply_kernel<<<SCAN_BLOCKS, 256, 0, stream>>>(deg, blocksum, rowstart, cur, src_csr);
  scatter_kernel<<<(E_BASE / 4 + 255) / 256, 256, 0, stream>>>(ei, cur, src_csr);

  // ---- prop 1 (beta = 1.0): h1 -> h2 (fp16) + invn2 (fused)
  prop_kernel<true, false><<<(N_NODES + 3) / 4, 256, 0, stream>>>(
      h1, invn1, src_csr, rowstart, nullptr, h2, invn2, nullptr, nullptr, nullptr);

  // ---- prop 2 (beta = beta2[0]) fused with lin2: h2 -> out (scalar per node)
  prop_kernel<false, true><<<(N_NODES + 3) / 4, 256, 0, stream>>>(
      h2, invn2, src_csr, rowstart, beta2, nullptr, nullptr, lin2_w, lin2_b, out);
}

// Round 10
// 297.676 us; speedup vs baseline: 2.2192x; 1.0101x over previous
//
#include <hip/hip_runtime.h>
#include <hip/hip_fp16.h>

#define N_NODES 50000
#define E_BASE  800000
#define IN_DIM  58
#define HID     100
#define HP2     128            // padded halves per feature row (256 B)
#define SCAN_BLOCKS ((N_NODES + 255) / 256)   // 196

// ---- lin1 + relu + fp16 quantize + fused invnorm (computed on quantized vals)
__global__ __launch_bounds__(256) void lin1_kernel(
    const float* __restrict__ x, const float* __restrict__ w,
    const float* __restrict__ b, __half* __restrict__ h,
    float* __restrict__ invn) {
  __shared__ alignas(16) float xs[64 * IN_DIM];    // [n][k] linear
  __shared__ alignas(16) float wsm[IN_DIM * HP2];  // [k][j], cols >=100 zero
  __shared__ float bl[HP2];
  int tid = threadIdx.x;
  int nb = blockIdx.x * 64;
  for (int i = tid; i < 64 * IN_DIM; i += 256) {
    int g = nb * IN_DIM + i;
    xs[i] = (g < N_NODES * IN_DIM) ? x[g] : 0.f;
  }
  for (int i = tid; i < IN_DIM * HP2; i += 256) {
    int k = i / HP2, j = i - k * HP2;
    wsm[i] = (j < HID) ? w[j * IN_DIM + k] : 0.f;
  }
  if (tid < HP2) bl[tid] = (tid < HID) ? b[tid] : 0.f;
  __syncthreads();
  int t_j = tid & 15, t_n = tid >> 4;
  float acc[4][8];
#pragma unroll
  for (int ni = 0; ni < 4; ++ni)
#pragma unroll
    for (int j = 0; j < 8; ++j) acc[ni][j] = bl[8 * t_j + j];
  for (int k = 0; k < IN_DIM; ++k) {
    float xv[4];
#pragma unroll
    for (int ni = 0; ni < 4; ++ni) xv[ni] = xs[(4 * t_n + ni) * IN_DIM + k];
    float4 wa = *(const float4*)&wsm[k * HP2 + 8 * t_j];
    float4 wb = *(const float4*)&wsm[k * HP2 + 8 * t_j + 4];
    float wv[8] = {wa.x, wa.y, wa.z, wa.w, wb.x, wb.y, wb.z, wb.w};
#pragma unroll
    for (int ni = 0; ni < 4; ++ni)
#pragma unroll
      for (int j = 0; j < 8; ++j) acc[ni][j] = fmaf(xv[ni], wv[j], acc[ni][j]);
  }
#pragma unroll
  for (int ni = 0; ni < 4; ++ni) {
    int n = nb + 4 * t_n + ni;
    uint4 st;
    ushort* sp = (ushort*)&st;
    float ss = 0.f;
#pragma unroll
    for (int j = 0; j < 8; ++j) {
      float v = fmaxf(acc[ni][j], 0.f);
      __half hv = __float2half_rn(v);
      sp[j] = __half_as_ushort(hv);
      float vq = __half2float(hv);
      ss = fmaf(vq, vq, ss);
    }
#pragma unroll
    for (int off = 1; off < 16; off <<= 1) ss += __shfl_xor(ss, off);
    if (n < N_NODES) {
      *((uint4*)(h + (size_t)n * HP2) + t_j) = st;
      if (t_j == 0) invn[n] = 1.f / fmaxf(sqrtf(ss), 1e-12f);
    }
  }
}

// --------------------------------- in-degree histogram (base edges, 4/thread)
__global__ __launch_bounds__(256) void hist_kernel(
    const int* __restrict__ ei, int* __restrict__ deg) {
  int i = blockIdx.x * 256 + threadIdx.x;
  if (i >= E_BASE / 4) return;
  int4 d4 = ((const int4*)(ei + E_BASE))[i];
  atomicAdd(&deg[d4.x], 1);
  atomicAdd(&deg[d4.y], 1);
  atomicAdd(&deg[d4.z], 1);
  atomicAdd(&deg[d4.w], 1);
}

// ------------------------------------------- hierarchical scan: block partials
// counts are deg[idx]+1 (implicit self loop)
__global__ __launch_bounds__(256) void scan_blocks_kernel(
    const int* __restrict__ deg, int* __restrict__ blocksum) {
  __shared__ int sh[4];
  int idx = blockIdx.x * 256 + threadIdx.x;
  int v = (idx < N_NODES) ? deg[idx] + 1 : 0;
#pragma unroll
  for (int off = 32; off; off >>= 1) v += __shfl_xor(v, off);
  if ((threadIdx.x & 63) == 0) sh[threadIdx.x >> 6] = v;
  __syncthreads();
  if (threadIdx.x == 0) blocksum[blockIdx.x] = sh[0] + sh[1] + sh[2] + sh[3];
}

// ---- scan apply with INTEGRATED top scan (each block redundantly scans the
// 196 block sums in LDS, sharing the same barriers as the per-element scan).
// Writes rowstart, cur (=start+1), and the self-loop edge into slot 0.
__global__ __launch_bounds__(256) void scan_apply_kernel(
    const int* __restrict__ deg, const int* __restrict__ blocksum,
    int* __restrict__ rowstart, int* __restrict__ cur,
    int* __restrict__ src_csr) {
  __shared__ int top[256];
  __shared__ int sh[256];
  int t = threadIdx.x;
  int idx = blockIdx.x * 256 + t;
  top[t] = (t < SCAN_BLOCKS) ? blocksum[t] : 0;
  int v = (idx < N_NODES) ? deg[idx] + 1 : 0;
  sh[t] = v;
  __syncthreads();
  for (int off = 1; off < 256; off <<= 1) {
    int a = (t >= off) ? top[t - off] : 0;
    int b = (t >= off) ? sh[t - off] : 0;
    __syncthreads();
    top[t] += a;
    sh[t] += b;
    __syncthreads();
  }
  int blockoff = (blockIdx.x == 0) ? 0 : top[blockIdx.x - 1];
  int excl = blockoff + sh[t] - v;
  if (idx < N_NODES) {
    rowstart[idx] = excl;
    src_csr[excl] = idx;      // self loop occupies slot 0, no atomic
    cur[idx] = excl + 1;
  }
  if (idx == N_NODES - 1) rowstart[N_NODES] = excl + v;
}

// --------------------------------------- scatter base edges into CSR, 4/thread
__global__ __launch_bounds__(256) void scatter_kernel(
    const int* __restrict__ ei, int* __restrict__ cur,
    int* __restrict__ src_csr) {
  int i = blockIdx.x * 256 + threadIdx.x;
  if (i >= E_BASE / 4) return;
  int4 s4 = ((const int4*)ei)[i];
  int4 d4 = ((const int4*)(ei + E_BASE))[i];
  int p;
  p = atomicAdd(&cur[d4.x], 1); src_csr[p] = s4.x;
  p = atomicAdd(&cur[d4.y], 1); src_csr[p] = s4.y;
  p = atomicAdd(&cur[d4.z], 1); src_csr[p] = s4.z;
  p = atomicAdd(&cur[d4.w], 1); src_csr[p] = s4.w;
}

// ---------------------------------------------------------------- fused prop
// One wave per node; EIGHT edges in parallel (8-lane groups, lane owns 16
// features = 2x dwordx4 per row) + 1-deep software pipeline: iteration r+1's
// full load chain (src_csr -> invn -> row) issues before iteration r's
// compute, hiding the dependent-gather latency. Fixed softmax max B=|beta|.
template<bool WRITE_INVN, bool FINAL>
__global__ __launch_bounds__(256) void prop_kernel(
    const __half* __restrict__ h, const float* __restrict__ invn,
    const int* __restrict__ src_csr, const int* __restrict__ rowstart,
    const float* __restrict__ beta_ptr,
    __half* __restrict__ out_feat, float* __restrict__ out_invn,
    const float* __restrict__ w2, const float* __restrict__ b2,
    float* __restrict__ out_scalar) {
  int node = (blockIdx.x * 256 + threadIdx.x) >> 6;
  int lane = threadIdx.x & 63;
  if (node >= N_NODES) return;
  int lq = lane & 7;         // feature slice: halves [16*lq, 16*lq+16)
  int q  = lane >> 3;        // edge sub-group 0..7
  float beta = beta_ptr ? beta_ptr[0] : 1.0f;
  float B = fabsf(beta);
  int start = rowstart[node], end = rowstart[node + 1];
  int deg = end - start;               // >= 1 (self loop)
  float ind = invn[node];
  const uint4* drow = (const uint4*)(h + (size_t)node * HP2);
  uint4 da = drow[2 * lq], db = drow[2 * lq + 1];
  float d[16];
  {
    const __half* ha = (const __half*)&da;
    const __half* hb = (const __half*)&db;
#pragma unroll
    for (int j = 0; j < 8; ++j) {
      d[j]     = __half2float(ha[j]) * ind;
      d[8 + j] = __half2float(hb[j]) * ind;
    }
  }
  float s = 0.f;
  float acc[16];
#pragma unroll
  for (int j = 0; j < 16; ++j) acc[j] = 0.f;
  int nt = (deg + 7) >> 3;
  // prologue: prefetch iteration 0 (invalid lanes read the self-loop slot —
  // always in-bounds, broadcast-friendly)
  bool valid = q < deg;
  int p0 = start + (valid ? q : 0);
  int sn = src_csr[p0];
  float iv = invn[sn];
  const uint4* rp = (const uint4*)(h + (size_t)sn * HP2);
  uint4 va = rp[2 * lq], vb = rp[2 * lq + 1];
  for (int r = 0; r < nt; ++r) {
    // ---- issue next iteration's load chain (wave-uniform branch)
    bool valid2 = false;
    float iv2 = 0.f;
    uint4 va2 = va, vb2 = vb;
    if (r + 1 < nt) {
      int e2 = 8 * (r + 1) + q;
      valid2 = e2 < deg;
      int p2 = start + (valid2 ? e2 : 0);
      int sn2 = src_csr[p2];
      iv2 = invn[sn2];
      const uint4* rp2 = (const uint4*)(h + (size_t)sn2 * HP2);
      va2 = rp2[2 * lq];
      vb2 = rp2[2 * lq + 1];
    }
    // ---- compute current iteration
    float vf[16];
    {
      const __half* ha = (const __half*)&va;
      const __half* hb = (const __half*)&vb;
#pragma unroll
      for (int j = 0; j < 8; ++j) {
        vf[j]     = __half2float(ha[j]);
        vf[8 + j] = __half2float(hb[j]);
      }
    }
    float t = 0.f;
#pragma unroll
    for (int j = 0; j < 16; ++j) t = fmaf(vf[j], d[j], t);
#pragma unroll
    for (int off = 1; off <= 4; off <<= 1) t += __shfl_xor(t, off);
    float a = valid ? beta * t * iv : -1e30f;
    float wgt = __expf(a - B);          // in (0, ~1]; 0 for invalid slots
    s += wgt;
#pragma unroll
    for (int j = 0; j < 16; ++j) acc[j] = fmaf(wgt, vf[j], acc[j]);
    // ---- rotate pipeline
    valid = valid2; iv = iv2; va = va2; vb = vb2;
  }
  // merge the 8 edge-groups (plain sums: shared fixed max B)
#pragma unroll
  for (int off = 8; off <= 32; off <<= 1) {
    s += __shfl_xor(s, off);
#pragma unroll
    for (int j = 0; j < 16; ++j) acc[j] += __shfl_xor(acc[j], off);
  }
  float invden = 1.f / (s + 1e-16f);
  if (!FINAL) {
    uint4 sta, stb;
    ushort* pa = (ushort*)&sta;
    ushort* pb = (ushort*)&stb;
    float ss = 0.f;
#pragma unroll
    for (int j = 0; j < 8; ++j) {
      __half hv = __float2half_rn(acc[j] * invden);
      pa[j] = __half_as_ushort(hv);
      float vq = __half2float(hv);
      ss = fmaf(vq, vq, ss);
    }
#pragma unroll
    for (int j = 0; j < 8; ++j) {
      __half hv = __float2half_rn(acc[8 + j] * invden);
      pb[j] = __half_as_ushort(hv);
      float vq = __half2float(hv);
      ss = fmaf(vq, vq, ss);
    }
    if (q == 0) {
      uint4* orow = (uint4*)(out_feat + (size_t)node * HP2);
      orow[2 * lq] = sta;
      orow[2 * lq + 1] = stb;
    }
    if (WRITE_INVN) {
#pragma unroll
      for (int off = 1; off <= 4; off <<= 1) ss += __shfl_xor(ss, off);
      if (lane == 0) out_invn[node] = 1.f / fmaxf(sqrtf(ss), 1e-12f);
    }
  } else {
    float qq = 0.f;
#pragma unroll
    for (int j = 0; j < 16; ++j) {
      int f = 16 * lq + j;
      float wv = (f < HID) ? w2[f] : 0.f;
      qq = fmaf(acc[j] * invden, wv, qq);
    }
#pragma unroll
    for (int off = 1; off <= 4; off <<= 1) qq += __shfl_xor(qq, off);
    if (lane == 0) out_scalar[node] = qq + b2[0];
  }
}

extern "C" void kernel_launch(void* const* d_in, const int* in_sizes, int n_in,
                              void* d_out, int out_size, void* d_ws, size_t ws_size,
                              hipStream_t stream) {
  const float* x      = (const float*)d_in[0];
  const int*   ei     = (const int*)d_in[1];     // [2][E_BASE], int32
  const float* lin1_w = (const float*)d_in[2];
  const float* lin1_b = (const float*)d_in[3];
  const float* beta2  = (const float*)d_in[4];
  const float* lin2_w = (const float*)d_in[5];
  const float* lin2_b = (const float*)d_in[6];
  float* out = (float*)d_out;

  // workspace layout
  char* wsb = (char*)d_ws;
  __half* h1 = (__half*)wsb;                       wsb += (size_t)N_NODES * HP2 * 2;
  __half* h2 = (__half*)wsb;                       wsb += (size_t)N_NODES * HP2 * 2;
  float* invn1 = (float*)wsb;                      wsb += N_NODES * 4;
  float* invn2 = (float*)wsb;                      wsb += N_NODES * 4;
  int* deg      = (int*)wsb;                       wsb += N_NODES * 4;
  int* rowstart = (int*)wsb;                       wsb += (N_NODES + 1) * 4;
  int* cur      = (int*)wsb;                       wsb += N_NODES * 4;
  int* src_csr  = (int*)wsb;                       wsb += (size_t)(E_BASE + N_NODES) * 4;
  int* blocksum = (int*)wsb;                       wsb += SCAN_BLOCKS * 4;

  // ---- lin1 + relu -> fp16 h1 + invn1 (fused)
  lin1_kernel<<<(N_NODES + 63) / 64, 256, 0, stream>>>(x, lin1_w, lin1_b, h1, invn1);

  // ---- build CSR by dst (self loop in slot 0 of each row, no atomics for it)
  hipMemsetAsync(deg, 0, N_NODES * sizeof(int), stream);
  hist_kernel<<<(E_BASE / 4 + 255) / 256, 256, 0, stream>>>(ei, deg);
  scan_blocks_kernel<<<SCAN_BLOCKS, 256, 0, stream>>>(deg, blocksum);
  scan_apply_kernel<<<SCAN_BLOCKS, 256, 0, stream>>>(deg, blocksum, rowstart, cur, src_csr);
  scatter_kernel<<<(E_BASE / 4 + 255) / 256, 256, 0, stream>>>(ei, cur, src_csr);

  // ---- prop 1 (beta = 1.0): h1 -> h2 (fp16) + invn2 (fused)
  prop_kernel<true, false><<<(N_NODES + 3) / 4, 256, 0, stream>>>(
      h1, invn1, src_csr, rowstart, nullptr, h2, invn2, nullptr, nullptr, nullptr);

  // ---- prop 2 (beta = beta2[0]) fused with lin2: h2 -> out (scalar per node)
  prop_kernel<false, true><<<(N_NODES + 3) / 4, 256, 0, stream>>>(
      h2, invn2, src_csr, rowstart, beta2, nullptr, nullptr, lin2_w, lin2_b, out);
}